// Round 14
// baseline (101.910 us; speedup 1.0000x reference)
//
#include <hip/hip_runtime.h>
#include <hip/hip_bf16.h>

#define D_MODEL 256
#define LQ 4800
#define NB 2
#define MROWS (NB * LQ)       // 9600
#define LN_EPS 1e-5f

typedef unsigned int u32;
typedef unsigned short u16;
typedef __attribute__((ext_vector_type(8))) short bf16x8;
typedef __attribute__((ext_vector_type(4))) float f32x4;
typedef __attribute__((ext_vector_type(2))) _Float16 f16x2;

__device__ __forceinline__ u16 f2bf(float f) {
    __hip_bfloat16 h = __float2bfloat16(f);
    return *reinterpret_cast<u16*>(&h);
}

// f16 pair dot into f32 (v_dot2_f32_f16)
__device__ __forceinline__ float dot2f16(u32 a, u32 b, float c) {
#if __has_builtin(__builtin_amdgcn_fdot2)
    return __builtin_amdgcn_fdot2(__builtin_bit_cast(f16x2, a),
                                  __builtin_bit_cast(f16x2, b), c, false);
#else
    f16x2 av = __builtin_bit_cast(f16x2, a), bv = __builtin_bit_cast(f16x2, b);
    c = fmaf((float)av.x, (float)bv.x, c);
    return fmaf((float)av.y, (float)bv.y, c);
#endif
}
__device__ __forceinline__ u32 pk_fma16(u32 a, u32 b, u32 c) {
    u32 d;
    asm("v_pk_fma_f16 %0, %1, %2, %3" : "=v"(d) : "v"(a), "v"(b), "v"(c));
    return d;
}
__device__ __forceinline__ u32 pk_add16(u32 a, u32 b) {
    u32 d;
    asm("v_pk_add_f16 %0, %1, %2" : "=v"(d) : "v"(a), "v"(b));
    return d;
}
__device__ __forceinline__ u32 pkrtz(float a, float b) {
    return __builtin_bit_cast(u32, __builtin_amdgcn_cvt_pkrtz(a, b));
}
__device__ __forceinline__ void gload_lds(const u16* src, u16* dst) {
    __builtin_amdgcn_global_load_lds(
        (const __attribute__((address_space(1))) u32*)src,
        (__attribute__((address_space(3))) u32*)dst, 16, 0, 0);
}

// ---------------------------------------------------------------------------
// Fused prep: cast x & source to bf16; transpose+cast all weights.
// grid: [0,2400) cast x, [2400,4800) cast source, [4800,7360) weight tiles.
// Wqkvt is [768][256]: rows 0..255 Wq^T, 256..511 Wk^T, 512..767 Wv^T.
// ---------------------------------------------------------------------------
__global__ __launch_bounds__(256) void prep_kernel(
    const float* __restrict__ x, const float* __restrict__ source,
    const float* __restrict__ Wq, const float* __restrict__ Wk,
    const float* __restrict__ Wv, const float* __restrict__ Wm,
    const float* __restrict__ W1, const float* __restrict__ W2,
    u16* __restrict__ xb, u16* __restrict__ sb,
    u16* __restrict__ Wqkvt, u16* __restrict__ Wmt,
    u16* __restrict__ W1t, u16* __restrict__ W2t)
{
    __shared__ float tile[16][17];
    const int t = threadIdx.x;
    int bid = blockIdx.x;

    if (bid < 4800) {
        const float* src = bid < 2400 ? x : source;
        u16* dst = bid < 2400 ? xb : sb;
        int b = bid < 2400 ? bid : bid - 2400;
        int i = (b * 256 + t) * 4;
        float4 v = *reinterpret_cast<const float4*>(src + i);
        ushort4 o; o.x = f2bf(v.x); o.y = f2bf(v.y); o.z = f2bf(v.z); o.w = f2bf(v.w);
        *reinterpret_cast<ushort4*>(dst + i) = o;
        return;
    }
    int sub = bid - 4800;
    const float* W; u16* Wt; int Nd, ldt, rowoff;
    if      (sub < 256)  { W = Wq; Wt = Wqkvt; Nd = 256; ldt = 256; rowoff = 0;   }
    else if (sub < 512)  { W = Wk; Wt = Wqkvt; Nd = 256; ldt = 256; rowoff = 256; sub -= 256; }
    else if (sub < 768)  { W = Wv; Wt = Wqkvt; Nd = 256; ldt = 256; rowoff = 512; sub -= 512; }
    else if (sub < 1024) { W = Wm; Wt = Wmt;   Nd = 256; ldt = 256; rowoff = 0;   sub -= 768; }
    else if (sub < 2048) { W = W1; Wt = W1t;   Nd = 512; ldt = 512; rowoff = 0;   sub -= 1024; }
    else                 { W = W2; Wt = W2t;   Nd = 256; ldt = 512; rowoff = 0;   sub -= 2048; }
    int ntiles = Nd >> 4;
    int tn = sub % ntiles, tk = sub / ntiles;
    int tx = t & 15, ty = t >> 4;
    tile[ty][tx] = W[(size_t)(tk * 16 + ty) * Nd + tn * 16 + tx];
    __syncthreads();
    Wt[(size_t)(rowoff + tn * 16 + ty) * ldt + tk * 16 + tx] = f2bf(tile[tx][ty]);
}

// ---------------------------------------------------------------------------
// bf16 MFMA GEMM, templated tile: C = act(A @ Bt^T). BK=32, 256 threads,
// 2x2 waves. flags: 1=relu, 2=bf16 out, 4=route by col>>8, 8=f16 out.
// ---------------------------------------------------------------------------
template<int BM, int BN>
__global__ __launch_bounds__(256) void gemm_mfma_kernel(
    const u16* __restrict__ A0, int lda0,
    const u16* __restrict__ A1, int lda1, int splitK, int nsel,
    const u16* __restrict__ Bt, int ldb,
    void* __restrict__ Cout,
    int M, int N, int K, int flags)
{
    __shared__ __align__(16) u16 As[BM * 32];
    __shared__ __align__(16) u16 Bs[BN * 32];

    constexpr int WM = BM / 2, WN = BN / 2;
    constexpr int FI = WM / 16, FJ = WN / 16;

    const int t  = threadIdx.x;
    const int l  = t & 63;
    const int w  = t >> 6;
    const int m0 = blockIdx.y * BM;
    const int n0 = blockIdx.x * BN;
    const int wr = w >> 1, wc = w & 1;

    if (nsel && n0 >= nsel) { A0 = A1; lda0 = lda1; }

    const int srow = l >> 2;
    const int sch  = (l & 3) ^ (srow & 3);

    f32x4 acc[FI][FJ];
#pragma unroll
    for (int i = 0; i < FI; ++i)
#pragma unroll
        for (int j = 0; j < FJ; ++j) acc[i][j] = (f32x4){0.f, 0.f, 0.f, 0.f};

    for (int k0 = 0; k0 < K; k0 += 32) {
        const u16* Ap; int kk, lda;
        if (splitK && k0 >= splitK) { Ap = A1; kk = k0 - splitK; lda = lda1; }
        else                        { Ap = A0; kk = k0;          lda = lda0; }

        if (BM >= 64) {
#pragma unroll
            for (int g = 0; g < BM / 64; ++g) {
                int grp = w * (BM / 64) + g;
                int row = grp * 16 + srow;
                gload_lds(Ap + (size_t)(m0 + row) * lda + kk + sch * 8, As + grp * 512);
            }
        } else if (w < BM / 16) {
            int row = w * 16 + srow;
            gload_lds(Ap + (size_t)(m0 + row) * lda + kk + sch * 8, As + w * 512);
        }
#pragma unroll
        for (int g = 0; g < BN / 64; ++g) {
            int grp = w * (BN / 64) + g;
            int row = grp * 16 + srow;
            gload_lds(Bt + (size_t)(n0 + row) * ldb + k0 + sch * 8, Bs + grp * 512);
        }
        __syncthreads();

        const int r  = l & 15;
        const int ch = l >> 4;
        bf16x8 af[FI], bfr[FJ];
#pragma unroll
        for (int i = 0; i < FI; ++i) {
            int ar = wr * WM + i * 16 + r;
            af[i] = *(const bf16x8*)((const char*)As + ar * 64 + ((ch ^ (r & 3)) * 16));
        }
#pragma unroll
        for (int j = 0; j < FJ; ++j) {
            int br = wc * WN + j * 16 + r;
            bfr[j] = *(const bf16x8*)((const char*)Bs + br * 64 + ((ch ^ (r & 3)) * 16));
        }
#pragma unroll
        for (int i = 0; i < FI; ++i)
#pragma unroll
            for (int j = 0; j < FJ; ++j)
                acc[i][j] = __builtin_amdgcn_mfma_f32_16x16x32_bf16(af[i], bfr[j], acc[i][j], 0, 0, 0);
        __syncthreads();
    }

    const int r  = l & 15;
    const int q4 = l >> 4;
#pragma unroll
    for (int i = 0; i < FI; ++i)
#pragma unroll
        for (int j = 0; j < FJ; ++j) {
            int col = n0 + wc * WN + j * 16 + r;
#pragma unroll
            for (int reg = 0; reg < 4; ++reg) {
                int row = m0 + wr * WM + i * 16 + q4 * 4 + reg;
                float vv = acc[i][j][reg];
                if (flags & 1) vv = fmaxf(vv, 0.f);
                size_t off;
                int colw, Nw;
                if (flags & 4) { off = (size_t)(col >> 8) * M * 256; colw = col & 255; Nw = 256; }
                else           { off = 0; colw = col; Nw = N; }
                if (flags & 8) {
                    _Float16 hv = (_Float16)vv;
                    ((u16*)Cout)[off + (size_t)row * Nw + colw] = __builtin_bit_cast(u16, hv);
                } else if (flags & 2) {
                    ((u16*)Cout)[off + (size_t)row * Nw + colw] = f2bf(vv);
                } else {
                    ((float*)Cout)[off + (size_t)row * Nw + colw] = vv;
                }
            }
        }
}

// ---------------------------------------------------------------------------
// GEMM (BM rows, N=256 full row) with fused LayerNorm epilogue.
// C_row = LN(A@Bt^T)[row] * g + b  (+ xres[row] if RESID). One block = BM rows.
// BM in {16, 32}: wave layout (BM/16) x (4/(BM/16)). OUT_BF16: bf16 else fp32.
// BM=16 -> 600 blocks over MROWS: 2.3 blocks/CU so barrier drains overlap.
// ---------------------------------------------------------------------------
template<int BM, bool RESID, bool OUT_BF16>
__global__ __launch_bounds__(256) void gemm_ln_kernel(
    const u16* __restrict__ A, int lda,
    const u16* __restrict__ Bt, int ldb,
    const float* __restrict__ g, const float* __restrict__ b,
    const float* __restrict__ xres,
    void* __restrict__ Cout, int K)
{
    constexpr int WAVES_M = BM / 16;          // 1 or 2
    constexpr int WAVES_N = 4 / WAVES_M;      // 4 or 2
    constexpr int WN = 256 / WAVES_N;         // 64 or 128
    constexpr int FJ = WN / 16;               // 4 or 8

    __shared__ __align__(16) u16 As[BM * 32];
    __shared__ __align__(16) u16 Bs[256 * 32];
    __shared__ float2 red[BM][WAVES_N];

    const int t  = threadIdx.x;
    const int l  = t & 63;
    const int w  = t >> 6;
    const int m0 = blockIdx.x * BM;
    const int wr = w / WAVES_N, wc = w % WAVES_N;

    const int srow = l >> 2;
    const int sch  = (l & 3) ^ (srow & 3);

    f32x4 acc[FJ];
#pragma unroll
    for (int j = 0; j < FJ; ++j) acc[j] = (f32x4){0.f, 0.f, 0.f, 0.f};

    for (int k0 = 0; k0 < K; k0 += 32) {
        if (w < WAVES_M) {   // A tile: BM rows, one 16-row group per wave
            int row = w * 16 + srow;
            gload_lds(A + (size_t)(m0 + row) * lda + k0 + sch * 8, As + w * 512);
        }
#pragma unroll
        for (int gg = 0; gg < 4; ++gg) {   // B tile: 256 rows, 4 groups/wave
            int grp = w * 4 + gg;
            int row = grp * 16 + srow;
            gload_lds(Bt + (size_t)row * ldb + k0 + sch * 8, Bs + grp * 512);
        }
        __syncthreads();

        const int r  = l & 15;
        const int ch = l >> 4;
        bf16x8 af = *(const bf16x8*)((const char*)As + (wr * 16 + r) * 64 + ((ch ^ (r & 3)) * 16));
#pragma unroll
        for (int j = 0; j < FJ; ++j) {
            int br = wc * WN + j * 16 + r;
            bf16x8 bf = *(const bf16x8*)((const char*)Bs + br * 64 + ((ch ^ (r & 3)) * 16));
            acc[j] = __builtin_amdgcn_mfma_f32_16x16x32_bf16(af, bf, acc[j], 0, 0, 0);
        }
        __syncthreads();
    }

    const int r  = l & 15;
    const int q4 = l >> 4;

    // ---- row partial sums over this thread's FJ cols ----
    float rs[4], rq[4];
#pragma unroll
    for (int reg = 0; reg < 4; ++reg) {
        float s = 0.f, sq = 0.f;
#pragma unroll
        for (int j = 0; j < FJ; ++j) { float vv = acc[j][reg]; s += vv; sq += vv * vv; }
        rs[reg] = s; rq[reg] = sq;
    }
#pragma unroll
    for (int off = 1; off <= 8; off <<= 1)
#pragma unroll
        for (int reg = 0; reg < 4; ++reg) {
            rs[reg] += __shfl_xor(rs[reg], off);
            rq[reg] += __shfl_xor(rq[reg], off);
        }
    if (r == 0)
#pragma unroll
        for (int reg = 0; reg < 4; ++reg)
            red[wr * 16 + q4 * 4 + reg][wc] = make_float2(rs[reg], rq[reg]);
    __syncthreads();

    // preload g,b for this thread's FJ cols
    float gj[FJ], bj[FJ];
#pragma unroll
    for (int j = 0; j < FJ; ++j) {
        int col = wc * WN + j * 16 + r;
        gj[j] = g[col]; bj[j] = b[col];
    }

#pragma unroll
    for (int reg = 0; reg < 4; ++reg) {
        int row = wr * 16 + q4 * 4 + reg;
        float sum = 0.f, sq = 0.f;
#pragma unroll
        for (int u = 0; u < WAVES_N; ++u) { sum += red[row][u].x; sq += red[row][u].y; }
        float mu  = sum * 0.00390625f;
        float var = sq * 0.00390625f - mu * mu;
        float rstd = rsqrtf(var + LN_EPS);
#pragma unroll
        for (int j = 0; j < FJ; ++j) {
            int col = wc * WN + j * 16 + r;
            float vv = (acc[j][reg] - mu) * rstd * gj[j] + bj[j];
            size_t oidx = (size_t)(m0 + row) * 256 + col;
            if (RESID) vv += xres[oidx];
            if (OUT_BF16) ((u16*)Cout)[oidx] = f2bf(vv);
            else          ((float*)Cout)[oidx] = vv;
        }
    }
}

// ---------------------------------------------------------------------------
// Gathered attention: wave = (query, head-pair), 128B oct-coalesced gathers.
// q,k,v: [MROWS,256] fp16 head-major. msg out: bf16. Block = 1 query, 4 waves.
// No LDS, no barriers. At the random-access L2-BW practical floor (~34 us).
// ---------------------------------------------------------------------------
__global__ __launch_bounds__(256, 8) void attn_kernel(
    const u16* __restrict__ q, const u16* __restrict__ k,
    const u16* __restrict__ v, const int* __restrict__ idx,
    u16* __restrict__ msg)
{
    const int t  = threadIdx.x;
    const int l  = t & 63;
    const int hp = t >> 6;              // head-pair 0..3
    const int qi = blockIdx.x;
    const int n  = qi / LQ;
    const size_t srcbase = (size_t)n * LQ * 256;   // u16 units

    const int o = l >> 3;   // key-set 0..7
    const int c = l & 7;    // 16B chunk of 128B slice

    const int* idxp = idx + (size_t)qi * 64;
    int rows[8];
#pragma unroll
    for (int i = 0; i < 8; ++i) rows[i] = idxp[i * 8 + o];   // 8-lane broadcast

    const size_t hoff = (size_t)hp * 64 + c * 8;   // u16 offset in a row

    // ---- K phase ----
    uint4 kd[8];
#pragma unroll
    for (int i = 0; i < 8; ++i)
        kd[i] = *(const uint4*)(k + srcbase + (size_t)rows[i] * 256 + hoff);
    uint4 qc = *(const uint4*)(q + (size_t)qi * 256 + hoff);

    float s[8];
#pragma unroll
    for (int i = 0; i < 8; ++i) {
        float si = 0.f;
        si = dot2f16(kd[i].x, qc.x, si);
        si = dot2f16(kd[i].y, qc.y, si);
        si = dot2f16(kd[i].z, qc.z, si);
        si = dot2f16(kd[i].w, qc.w, si);
        si += __shfl_xor(si, 1);
        si += __shfl_xor(si, 2);
        s[i] = si * 0.17677669529663687f;
    }

    // ---- V phase: kd dead; latency hides under softmax ----
    uint4 vd[8];
#pragma unroll
    for (int i = 0; i < 8; ++i)
        vd[i] = *(const uint4*)(v + srcbase + (size_t)rows[i] * 256 + hoff);

    // ---- softmax over 64 keys ----
    float mx = s[0];
#pragma unroll
    for (int i = 1; i < 8; ++i) mx = fmaxf(mx, s[i]);
    mx = fmaxf(mx, __shfl_xor(mx, 8));
    mx = fmaxf(mx, __shfl_xor(mx, 16));
    mx = fmaxf(mx, __shfl_xor(mx, 32));
    float p[8], sum = 0.f;
#pragma unroll
    for (int i = 0; i < 8; ++i) { p[i] = __expf(s[i] - mx); sum += p[i]; }
    sum += __shfl_xor(sum, 8);
    sum += __shfl_xor(sum, 16);
    sum += __shfl_xor(sum, 32);
    float inv = 1.f / sum;

    // ---- PV: 8 keys x 4 dim-pair u32s, f16 packed fma ----
    u32 A0 = 0, A1 = 0, A2 = 0, A3 = 0;
#pragma unroll
    for (int i = 0; i < 8; ++i) {
        float pi = p[i] * inv;
        u32 pp = pkrtz(pi, pi);
        A0 = pk_fma16(pp, vd[i].x, A0);
        A1 = pk_fma16(pp, vd[i].y, A1);
        A2 = pk_fma16(pp, vd[i].z, A2);
        A3 = pk_fma16(pp, vd[i].w, A3);
    }

    // ---- split-reduce over the 8 o-sets ----
    const bool ob0 = (o & 1) != 0;
    const bool ob1 = (o & 2) != 0;
    {
        u32 t0 = ob0 ? A0 : A2;
        u32 t1 = ob0 ? A1 : A3;
        t0 = __shfl_xor((int)t0, 8);
        t1 = __shfl_xor((int)t1, 8);
        A0 = pk_add16(ob0 ? A2 : A0, t0);
        A1 = pk_add16(ob0 ? A3 : A1, t1);
    }
    {
        u32 u0 = ob1 ? A0 : A1;
        u0 = __shfl_xor((int)u0, 16);
        A0 = pk_add16(ob1 ? A1 : A0, u0);
    }
    A0 = pk_add16(A0, (u32)__shfl_xor((int)A0, 32));

    if (o < 4) {
        int j = 2 * (o & 1) + ((o >> 1) & 1);
        f16x2 hv = __builtin_bit_cast(f16x2, A0);
        u32 packed = (u32)f2bf((float)hv.x) | ((u32)f2bf((float)hv.y) << 16);
        *(u32*)(msg + (size_t)qi * 256 + hp * 64 + c * 8 + j * 2) = packed;
    }
}

// ---------------------------------------------------------------------------
extern "C" void kernel_launch(void* const* d_in, const int* in_sizes, int n_in,
                              void* d_out, int out_size, void* d_ws, size_t ws_size,
                              hipStream_t stream)
{
    const float* x      = (const float*)d_in[0];
    const float* source = (const float*)d_in[1];
    const int*   eidx   = (const int*)d_in[2];
    const float* Wq     = (const float*)d_in[3];
    const float* Wk     = (const float*)d_in[4];
    const float* Wv     = (const float*)d_in[5];
    const float* Wm     = (const float*)d_in[6];
    const float* W1     = (const float*)d_in[7];
    const float* W2     = (const float*)d_in[8];
    const float* g1     = (const float*)d_in[9];
    const float* b1     = (const float*)d_in[10];
    const float* g2     = (const float*)d_in[11];
    const float* b2     = (const float*)d_in[12];
    float* out = (float*)d_out;

    char* ws = (char*)d_ws;
    const size_t SZB = (size_t)MROWS * 256 * 2;    // 4.9 MB
    u16* xb     = (u16*)(ws);                      // bf16, live until W1 gemm
    u16* sb     = (u16*)(ws + SZB);                // bf16, dead after qkv gemm
    u16* qb     = (u16*)(ws + 2 * SZB);            // f16, qkv gemm seg 0
    u16* kb     = (u16*)(ws + 3 * SZB);            // f16, seg 1
    u16* vb     = (u16*)(ws + 4 * SZB);            // f16, seg 2
    u16* msgb   = (u16*)(ws + 5 * SZB);            // bf16 attn output
    u16* msglnb = (u16*)(ws + 6 * SZB);            // bf16 LN1 output
    u16* h1b    = (u16*)(ws + 7 * SZB);            // bf16 [9600][512]
    u16* Wqkvt  = (u16*)(ws + 9 * SZB);            // [768][256]
    u16* Wmt    = Wqkvt + 768 * 256;
    u16* W1t    = Wmt + 256 * 256;                 // [512][512]
    u16* W2t    = W1t + 512 * 512;                 // [256][512]

    dim3 blk(256);

    // fused prep: casts + all weight transposes
    prep_kernel<<<dim3(7360), blk, 0, stream>>>(x, source, Wq, Wk, Wv, Wm, W1, W2,
                                                xb, sb, Wqkvt, Wmt, W1t, W2t);

    // fused q|k|v projection, f16 out, 64x128 tiles (900 blocks)
    gemm_mfma_kernel<64, 128><<<dim3(6, 150), blk, 0, stream>>>(
        xb, 256, sb, 256, 0, 256, Wqkvt, 256, qb, MROWS, 768, 256, 8 | 4);

    // gathered attention -> msg (bf16); one block per query
    attn_kernel<<<dim3(MROWS), blk, 0, stream>>>(qb, kb, vb, eidx, msgb);

    // msg @ Wm + LN1 fused -> bf16 msglnb (600 blocks of 16 rows)
    gemm_ln_kernel<16, false, true><<<dim3(600), blk, 0, stream>>>(
        msgb, 256, Wmt, 256, g1, b1, nullptr, msglnb, 256);

    // concat(x, msgln) @ W1, relu -> bf16 [9600,512] (64x128 tiles, 600 blocks)
    gemm_mfma_kernel<64, 128><<<dim3(4, 150), blk, 0, stream>>>(
        xb, 256, msglnb, 256, 256, 0, W1t, 512, h1b, MROWS, 512, 512, 1 | 2);

    // h1 @ W2 + LN2 + residual fused -> fp32 out (600 blocks of 16 rows)
    gemm_ln_kernel<16, true, false><<<dim3(600), blk, 0, stream>>>(
        h1b, 512, W2t, 512, g2, b2, x, out, 512);
}